// Round 1
// baseline (119.704 us; speedup 1.0000x reference)
//
#include <hip/hip_runtime.h>
#include <math.h>

// Problem constants (from reference): x [B=1024, S=256, E=4] fp32.
constexpr int S  = 256;
constexpr int E  = 4;
constexpr int H1 = 8;
constexpr int H2 = 4;

// One block per batch element, one thread per query row.
// k/v rows staged in LDS (4 KB each); j-loop LDS reads are wave-uniform
// (broadcast, no bank conflicts). Two-pass softmax is branch-free.
__global__ __launch_bounds__(S) void attn_mlp_kernel(
    const float* __restrict__ x,
    const float* __restrict__ Wq, const float* __restrict__ Wk, const float* __restrict__ Wv,
    const float* __restrict__ W1, const float* __restrict__ b1,
    const float* __restrict__ W2, const float* __restrict__ b2,
    const float* __restrict__ W3, const float* __restrict__ b3,
    float* __restrict__ out)
{
    const int b = blockIdx.x;
    const int t = threadIdx.x;

    __shared__ float k_lds[S][E];
    __shared__ float v_lds[S][E];

    // x row: 16 B aligned float4 load
    const float4 xr = *reinterpret_cast<const float4*>(x + ((size_t)b * S + t) * E);
    const float xv[E] = {xr.x, xr.y, xr.z, xr.w};

    // q, k, v = x @ W  (weights are tiny, uniform-address loads -> L1/scalar)
    float q[E];
    #pragma unroll
    for (int e = 0; e < E; ++e) {
        float aq = 0.f, ak = 0.f, av = 0.f;
        #pragma unroll
        for (int i = 0; i < E; ++i) {
            aq = fmaf(xv[i], Wq[i * E + e], aq);
            ak = fmaf(xv[i], Wk[i * E + e], ak);
            av = fmaf(xv[i], Wv[i * E + e], av);
        }
        q[e] = aq * 0.5f;        // fold 1/sqrt(E) into q
        k_lds[t][e] = ak;
        v_lds[t][e] = av;
    }
    __syncthreads();

    // Pass 1: row max of scores (needed: |s| can reach ~100, exp would overflow)
    float m = -3.0e38f;
    #pragma unroll 8
    for (int j = 0; j < S; ++j) {
        float s = q[0] * k_lds[j][0];
        s = fmaf(q[1], k_lds[j][1], s);
        s = fmaf(q[2], k_lds[j][2], s);
        s = fmaf(q[3], k_lds[j][3], s);
        m = fmaxf(m, s);
    }

    // Pass 2: exp-sum + PV accumulate
    float l = 0.f;
    float acc[E] = {0.f, 0.f, 0.f, 0.f};
    #pragma unroll 4
    for (int j = 0; j < S; ++j) {
        float s = q[0] * k_lds[j][0];
        s = fmaf(q[1], k_lds[j][1], s);
        s = fmaf(q[2], k_lds[j][2], s);
        s = fmaf(q[3], k_lds[j][3], s);
        const float p = __expf(s - m);
        l += p;
        #pragma unroll
        for (int e = 0; e < E; ++e) acc[e] = fmaf(p, v_lds[j][e], acc[e]);
    }
    const float inv = 1.0f / l;

    float a[E];
    #pragma unroll
    for (int e = 0; e < E; ++e) a[e] = acc[e] * inv;

    // Regressor: Linear(4->8) tanh, Linear(8->4) tanh, Linear(4->1)
    float h1[H1];
    #pragma unroll
    for (int o = 0; o < H1; ++o) {
        float s = b1[o];
        #pragma unroll
        for (int i = 0; i < E; ++i) s = fmaf(a[i], W1[i * H1 + o], s);
        h1[o] = tanhf(s);
    }
    float h2[H2];
    #pragma unroll
    for (int o = 0; o < H2; ++o) {
        float s = b2[o];
        #pragma unroll
        for (int i = 0; i < H1; ++i) s = fmaf(h1[i], W2[i * H2 + o], s);
        h2[o] = tanhf(s);
    }
    float r = b3[0];
    #pragma unroll
    for (int i = 0; i < H2; ++i) r = fmaf(h2[i], W3[i], r);

    out[(size_t)b * S + t] = r;
}

extern "C" void kernel_launch(void* const* d_in, const int* in_sizes, int n_in,
                              void* d_out, int out_size, void* d_ws, size_t ws_size,
                              hipStream_t stream) {
    const float* x  = (const float*)d_in[0];
    const float* Wq = (const float*)d_in[1];
    const float* Wk = (const float*)d_in[2];
    const float* Wv = (const float*)d_in[3];
    const float* W1 = (const float*)d_in[4];
    const float* b1 = (const float*)d_in[5];
    const float* W2 = (const float*)d_in[6];
    const float* b2 = (const float*)d_in[7];
    const float* W3 = (const float*)d_in[8];
    const float* b3 = (const float*)d_in[9];
    float* out = (float*)d_out;

    const int B = in_sizes[0] / (S * E);   // 1024
    attn_mlp_kernel<<<dim3(B), dim3(S), 0, stream>>>(
        x, Wq, Wk, Wv, W1, b1, W2, b2, W3, b3, out);
}

// Round 2
// 99.929 us; speedup vs baseline: 1.1979x; 1.1979x over previous
//
#include <hip/hip_runtime.h>
#include <math.h>

// x [B=1024, S=256, E=4] fp32. One block = one batch (256 threads, 4 waves).
// Phase 1: thread t computes q/k/v for row t -> LDS (q scaled by 1/sqrt(E)).
// Phase 2: wave w scans key chunk [w*64, w*64+64) for ALL 256 rows
//          (4 rows per lane) -> each LDS broadcast read feeds 4 rows of FMA,
//          cutting LDS instruction count 4x vs one-row-per-thread.
// Phase 3: flash-style merge of the 4 waves' partial (m, l, acc) per row,
//          then the tiny MLP and the store.
constexpr int S  = 256;
constexpr int E  = 4;
constexpr int H1 = 8;
constexpr int H2 = 4;
constexpr int NW    = 4;       // waves per block
constexpr int CHUNK = S / NW;  // 64 keys per wave
constexpr int R     = 4;       // rows per lane (64 lanes * 4 = 256 rows)

__global__ __launch_bounds__(256, 4) void attn_mlp_kernel(
    const float* __restrict__ x,
    const float* __restrict__ Wq, const float* __restrict__ Wk, const float* __restrict__ Wv,
    const float* __restrict__ W1, const float* __restrict__ b1,
    const float* __restrict__ W2, const float* __restrict__ b2,
    const float* __restrict__ W3, const float* __restrict__ b3,
    float* __restrict__ out)
{
    const int b    = blockIdx.x;
    const int tid  = threadIdx.x;
    const int w    = tid >> 6;
    const int lane = tid & 63;

    __shared__ float4 q_lds[S];
    __shared__ float4 k_lds[S];
    __shared__ float4 v_lds[S];
    __shared__ float2 ml_lds[NW][S];   // (m, l) partials
    __shared__ float4 acc_lds[NW][S];  // acc partials

    // ---- Phase 1: q/k/v for row tid ----
    const float4 xr = *reinterpret_cast<const float4*>(x + ((size_t)b * S + tid) * E);
    const float xv[E] = {xr.x, xr.y, xr.z, xr.w};
    {
        float4 q, k, v;
        float* qp = &q.x; float* kp = &k.x; float* vp = &v.x;
        #pragma unroll
        for (int e = 0; e < E; ++e) {
            float aq = 0.f, ak = 0.f, av = 0.f;
            #pragma unroll
            for (int i = 0; i < E; ++i) {
                aq = fmaf(xv[i], Wq[i * E + e], aq);
                ak = fmaf(xv[i], Wk[i * E + e], ak);
                av = fmaf(xv[i], Wv[i * E + e], av);
            }
            qp[e] = aq * 0.5f;   // fold 1/sqrt(E)
            kp[e] = ak;
            vp[e] = av;
        }
        q_lds[tid] = q; k_lds[tid] = k; v_lds[tid] = v;
    }
    __syncthreads();

    // ---- Phase 2: wave w scans keys [j0, j0+CHUNK) for rows {lane + 64*rr} ----
    const int j0 = w * CHUNK;
    float4 qr[R];
    #pragma unroll
    for (int rr = 0; rr < R; ++rr) qr[rr] = q_lds[lane + 64 * rr];

    float m[R];
    #pragma unroll
    for (int rr = 0; rr < R; ++rr) m[rr] = -3.0e38f;

    #pragma unroll 4
    for (int j = 0; j < CHUNK; ++j) {
        const float4 k = k_lds[j0 + j];
        #pragma unroll
        for (int rr = 0; rr < R; ++rr) {
            float s = qr[rr].x * k.x;
            s = fmaf(qr[rr].y, k.y, s);
            s = fmaf(qr[rr].z, k.z, s);
            s = fmaf(qr[rr].w, k.w, s);
            m[rr] = fmaxf(m[rr], s);
        }
    }

    float l[R];
    float4 acc[R];
    #pragma unroll
    for (int rr = 0; rr < R; ++rr) {
        l[rr] = 0.f;
        acc[rr] = make_float4(0.f, 0.f, 0.f, 0.f);
    }

    #pragma unroll 4
    for (int j = 0; j < CHUNK; ++j) {
        const float4 k = k_lds[j0 + j];
        const float4 v = v_lds[j0 + j];
        #pragma unroll
        for (int rr = 0; rr < R; ++rr) {
            float s = qr[rr].x * k.x;
            s = fmaf(qr[rr].y, k.y, s);
            s = fmaf(qr[rr].z, k.z, s);
            s = fmaf(qr[rr].w, k.w, s);
            const float p = __expf(s - m[rr]);
            l[rr] += p;
            acc[rr].x = fmaf(p, v.x, acc[rr].x);
            acc[rr].y = fmaf(p, v.y, acc[rr].y);
            acc[rr].z = fmaf(p, v.z, acc[rr].z);
            acc[rr].w = fmaf(p, v.w, acc[rr].w);
        }
    }

    #pragma unroll
    for (int rr = 0; rr < R; ++rr) {
        const int row = lane + 64 * rr;
        ml_lds[w][row]  = make_float2(m[rr], l[rr]);
        acc_lds[w][row] = acc[rr];
    }
    __syncthreads();

    // ---- Phase 3: merge the 4 partials for row tid, then MLP ----
    float mstar = -3.0e38f;
    float2 mlw[NW];
    #pragma unroll
    for (int ww = 0; ww < NW; ++ww) {
        mlw[ww] = ml_lds[ww][tid];
        mstar = fmaxf(mstar, mlw[ww].x);
    }
    float lsum = 0.f;
    float ax = 0.f, ay = 0.f, az = 0.f, aw = 0.f;
    #pragma unroll
    for (int ww = 0; ww < NW; ++ww) {
        const float c = __expf(mlw[ww].x - mstar);
        lsum = fmaf(mlw[ww].y, c, lsum);
        const float4 a4 = acc_lds[ww][tid];
        ax = fmaf(a4.x, c, ax);
        ay = fmaf(a4.y, c, ay);
        az = fmaf(a4.z, c, az);
        aw = fmaf(a4.w, c, aw);
    }
    const float inv = 1.0f / lsum;
    const float a[E] = {ax * inv, ay * inv, az * inv, aw * inv};

    float h1[H1];
    #pragma unroll
    for (int o = 0; o < H1; ++o) {
        float s = b1[o];
        #pragma unroll
        for (int i = 0; i < E; ++i) s = fmaf(a[i], W1[i * H1 + o], s);
        h1[o] = tanhf(s);
    }
    float h2[H2];
    #pragma unroll
    for (int o = 0; o < H2; ++o) {
        float s = b2[o];
        #pragma unroll
        for (int i = 0; i < H1; ++i) s = fmaf(h1[i], W2[i * H2 + o], s);
        h2[o] = tanhf(s);
    }
    float r = b3[0];
    #pragma unroll
    for (int i = 0; i < H2; ++i) r = fmaf(h2[i], W3[i], r);

    out[(size_t)b * S + tid] = r;
}

extern "C" void kernel_launch(void* const* d_in, const int* in_sizes, int n_in,
                              void* d_out, int out_size, void* d_ws, size_t ws_size,
                              hipStream_t stream) {
    const float* x  = (const float*)d_in[0];
    const float* Wq = (const float*)d_in[1];
    const float* Wk = (const float*)d_in[2];
    const float* Wv = (const float*)d_in[3];
    const float* W1 = (const float*)d_in[4];
    const float* b1 = (const float*)d_in[5];
    const float* W2 = (const float*)d_in[6];
    const float* b2 = (const float*)d_in[7];
    const float* W3 = (const float*)d_in[8];
    const float* b3 = (const float*)d_in[9];
    float* out = (float*)d_out;

    const int B = in_sizes[0] / (S * E);   // 1024
    attn_mlp_kernel<<<dim3(B), dim3(256), 0, stream>>>(
        x, Wq, Wk, Wv, W1, b1, W2, b2, W3, b3, out);
}